// Round 1
// baseline (445.402 us; speedup 1.0000x reference)
//
#include <hip/hip_runtime.h>
#include <hip/hip_bf16.h>
#include <stdint.h>

// LSTM block: pre = [x|h_prev] @ [Wx|Rh]^T + bias, gates z,i,f,o; c = f*c_prev + i*z; h = o*tanh(c)
// GEMM M=16384 N=4096(=4H gate-interleaved n'=4h+g) K=2048, bf16 MFMA, fused epilogue.

typedef __attribute__((ext_vector_type(8))) short bf16x8;
typedef __attribute__((ext_vector_type(4))) float f32x4;
typedef __attribute__((ext_vector_type(8))) unsigned short u16x8;

#define AS1 __attribute__((address_space(1)))
#define AS3 __attribute__((address_space(3)))

constexpr int BATCH = 16384;
constexpr int HDIM  = 1024;
constexpr int KDIM  = 2048;   // I + H
constexpr int NDIM  = 4096;   // 4*H

__device__ inline unsigned short f2bf(float f) {
  uint32_t u = __builtin_bit_cast(uint32_t, f);
  u += 0x7fffu + ((u >> 16) & 1u);   // round-to-nearest-even
  return (unsigned short)(u >> 16);
}

__device__ inline u16x8 cvt8(const float* __restrict__ src) {
  float4 f0 = *(const float4*)src;
  float4 f1 = *(const float4*)(src + 4);
  u16x8 v;
  v[0] = f2bf(f0.x); v[1] = f2bf(f0.y); v[2] = f2bf(f0.z); v[3] = f2bf(f0.w);
  v[4] = f2bf(f1.x); v[5] = f2bf(f1.y); v[6] = f2bf(f1.z); v[7] = f2bf(f1.w);
  return v;
}

__device__ inline float sigmoid_f(float x) {
  float e = __builtin_amdgcn_exp2f(-1.4426950408889634f * x);
  return __builtin_amdgcn_rcpf(1.0f + e);
}
__device__ inline float tanh_f(float x) {
  float e = __builtin_amdgcn_exp2f(2.8853900817779268f * x);  // e^(2x)
  return 1.0f - 2.0f * __builtin_amdgcn_rcpf(1.0f + e);
}

// XH[b][k] = bf16( k<1024 ? x[b][k] : h_prev[b][k-1024] )
__global__ void pack_xh(const float* __restrict__ x, const float* __restrict__ hp,
                        unsigned short* __restrict__ xh) {
  const int64_t nch = (int64_t)BATCH * KDIM / 8;
  for (int64_t c = (int64_t)blockIdx.x * blockDim.x + threadIdx.x; c < nch;
       c += (int64_t)gridDim.x * blockDim.x) {
    const int b = (int)(c >> 8);          // 256 8-elem chunks per row
    const int k = ((int)c & 255) * 8;
    const float* src = (k < 1024) ? (x + (int64_t)b * 1024 + k)
                                  : (hp + (int64_t)b * 1024 + (k - 1024));
    *(u16x8*)(xh + c * 8) = cvt8(src);
  }
}

// Wp[n'][k], n' = 4*h+g: k<1024 -> Wx[g][h][k], else Rh[g][h][k-1024]
__global__ void pack_w(const float* __restrict__ Wx, const float* __restrict__ Rh,
                       unsigned short* __restrict__ wp) {
  const int64_t nch = (int64_t)NDIM * KDIM / 8;
  for (int64_t c = (int64_t)blockIdx.x * blockDim.x + threadIdx.x; c < nch;
       c += (int64_t)gridDim.x * blockDim.x) {
    const int np = (int)(c >> 8);
    const int k = ((int)c & 255) * 8;
    const int h = np >> 2, g = np & 3;
    const float* src = (k < 1024) ? (Wx + (int64_t)(g * HDIM + h) * 1024 + k)
                                  : (Rh + (int64_t)(g * HDIM + h) * 1024 + (k - 1024));
    *(u16x8*)(wp + c * 8) = cvt8(src);
  }
}

__global__ void pack_bias(const float* __restrict__ bx, const float* __restrict__ bh,
                          float* __restrict__ bias) {
  int n = blockIdx.x * blockDim.x + threadIdx.x;
  if (n < NDIM) {
    int h = n >> 2, g = n & 3;
    bias[n] = bx[g * HDIM + h] + bh[g * HDIM + h];
  }
}

// 128x128 tile GEMM (m97 structure) + fused LSTM epilogue.
__global__ __launch_bounds__(256) void lstm_gemm(
    const unsigned short* __restrict__ XH, const unsigned short* __restrict__ Wp,
    const float* __restrict__ bias, const float* __restrict__ c_prev,
    float* __restrict__ out_h, float* __restrict__ out_c) {
  __shared__ unsigned short Alds[128 * 64];   // [row][k] row-major, 16KB
  __shared__ unsigned short Blds[128 * 64];   // [n'][k] row-major, 16KB
  __shared__ float Elds[4][16 * 68];          // per-wave epilogue transpose, padded

  const int tid  = threadIdx.x;
  const int lane = tid & 63;
  const int w    = tid >> 6;
  const int wr   = w >> 1, wc = w & 1;

  // XCD-aware swizzle: xcd owns 4 tile_n columns (B-panel 2MB, L2-resident);
  // consecutive q share tile_m (A-panel L2 reuse across the 4 tile_n).
  const int bid = blockIdx.x;
  const int xcd = bid & 7;
  const int q   = bid >> 3;
  const int tn  = xcd * 4 + (q & 3);
  const int tm  = q >> 2;
  const int m0  = tm * 128;
  const int n0  = tn * 128;

  // global staging pointers: thread loads row (s*32 + tid/8), 8 bf16 at col (tid&7)*8
  const char* agp = (const char*)XH + ((int64_t)(m0 + (tid >> 3)) * KDIM + (tid & 7) * 8) * 2;
  const char* bgp = (const char*)Wp + ((int64_t)(n0 + (tid >> 3)) * KDIM + (tid & 7) * 8) * 2;
  char* aldsw = (char*)Alds + w * 1024;   // wave-uniform LDS dest base
  char* bldsw = (char*)Blds + w * 1024;

  const int la = lane & 15;
  const int kg = lane >> 4;
  const uint32_t aoff0 = (uint32_t)(64 * wr + la) * 128 + kg * 16;
  const uint32_t boff0 = (uint32_t)(64 * wc + la) * 128 + kg * 16;

  f32x4 acc[4][4] = {};

  for (int kt = 0; kt < KDIM / 64; ++kt) {
#pragma unroll
    for (int s = 0; s < 4; ++s)
      __builtin_amdgcn_global_load_lds((const AS1 void*)(agp + (int64_t)s * 131072 + kt * 128),
                                       (AS3 void*)(aldsw + s * 4096), 16, 0, 0);
#pragma unroll
    for (int s = 0; s < 4; ++s)
      __builtin_amdgcn_global_load_lds((const AS1 void*)(bgp + (int64_t)s * 131072 + kt * 128),
                                       (AS3 void*)(bldsw + s * 4096), 16, 0, 0);
    __syncthreads();
#pragma unroll
    for (int kh = 0; kh < 2; ++kh) {
      bf16x8 af[4], bfr[4];
#pragma unroll
      for (int mi = 0; mi < 4; ++mi)
        af[mi] = *(const bf16x8*)((const char*)Alds + aoff0 + mi * 2048 + kh * 64);
#pragma unroll
      for (int ni = 0; ni < 4; ++ni)
        bfr[ni] = *(const bf16x8*)((const char*)Blds + boff0 + ni * 2048 + kh * 64);
#pragma unroll
      for (int mi = 0; mi < 4; ++mi)
#pragma unroll
        for (int ni = 0; ni < 4; ++ni)
          acc[mi][ni] = __builtin_amdgcn_mfma_f32_16x16x32_bf16(af[mi], bfr[ni], acc[mi][ni], 0, 0, 0);
    }
    __syncthreads();
  }

  // ---- fused epilogue ----
  // wave owns rows [m0+64wr, +64), cols n' [n0+64wc, +64) -> h in [hbase, hbase+16)
  const int hbase = (n0 + 64 * wc) >> 2;
  const float4 bias4 = *(const float4*)(bias + n0 + 64 * wc + 4 * la);
  float* ew = Elds[w];

#pragma unroll
  for (int mi = 0; mi < 4; ++mi) {
    // stash 16x64 fp32 fragment block (wave-private; no barrier needed)
#pragma unroll
    for (int ni = 0; ni < 4; ++ni)
#pragma unroll
      for (int r = 0; r < 4; ++r)
        ew[(4 * kg + r) * 68 + ni * 16 + la] = acc[mi][ni][r];
#pragma unroll
    for (int p = 0; p < 4; ++p) {
      const int row = p * 4 + kg;
      float4 g4 = *(const float4*)(ew + row * 68 + 4 * la);   // z,i,f,o for one (b,h)
      const int b  = m0 + 64 * wr + mi * 16 + row;
      const int hg = hbase + la;
      const uint32_t oidx = (uint32_t)b * HDIM + (uint32_t)hg;
      const float cp = c_prev[oidx];
      const float zg = tanh_f(g4.x + bias4.x);
      const float ig = sigmoid_f(g4.y + bias4.y);
      const float fg = sigmoid_f(g4.z + bias4.z);
      const float og = sigmoid_f(g4.w + bias4.w);
      const float cn = fg * cp + ig * zg;
      out_h[oidx] = og * tanh_f(cn);
      out_c[oidx] = cn;
    }
  }
}

extern "C" void kernel_launch(void* const* d_in, const int* in_sizes, int n_in,
                              void* d_out, int out_size, void* d_ws, size_t ws_size,
                              hipStream_t stream) {
  const float* x  = (const float*)d_in[0];
  const float* hp = (const float*)d_in[1];
  const float* cp = (const float*)d_in[2];
  const float* Wx = (const float*)d_in[3];
  const float* bx = (const float*)d_in[4];
  const float* Rh = (const float*)d_in[5];
  const float* bh = (const float*)d_in[6];

  unsigned short* XH = (unsigned short*)d_ws;                 // 64 MB
  unsigned short* Wp = XH + (size_t)BATCH * KDIM;             // 16 MB
  float* bias = (float*)(Wp + (size_t)NDIM * KDIM);           // 16 KB
  float* out_h = (float*)d_out;
  float* out_c = out_h + (size_t)BATCH * HDIM;

  pack_xh<<<2048, 256, 0, stream>>>(x, hp, XH);
  pack_w<<<1024, 256, 0, stream>>>(Wx, Rh, Wp);
  pack_bias<<<16, 256, 0, stream>>>(bx, bh, bias);
  lstm_gemm<<<4096, 256, 0, stream>>>(XH, Wp, bias, cp, out_h, out_c);
}

// Round 2
// 353.816 us; speedup vs baseline: 1.2589x; 1.2589x over previous
//
#include <hip/hip_runtime.h>
#include <hip/hip_bf16.h>
#include <stdint.h>

// LSTM block: pre = [x|h_prev] @ [Wx|Rh]^T + bias, gates z,i,f,o; c = f*c_prev + i*z; h = o*tanh(c)
// GEMM M=16384 N=4096(=4H gate-interleaved n'=4h+g) K=2048, bf16 MFMA, fused epilogue.
// R2: XOR bank-conflict swizzle (pre-swizzled global source for global_load_lds,
//     matching XOR on ds_read) + epilogue LDS union (50KB -> 32KB, 3 -> 5 blocks/CU).

typedef __attribute__((ext_vector_type(8))) short bf16x8;
typedef __attribute__((ext_vector_type(4))) float f32x4;
typedef __attribute__((ext_vector_type(8))) unsigned short u16x8;

#define AS1 __attribute__((address_space(1)))
#define AS3 __attribute__((address_space(3)))

constexpr int BATCH = 16384;
constexpr int HDIM  = 1024;
constexpr int KDIM  = 2048;   // I + H
constexpr int NDIM  = 4096;   // 4*H

__device__ inline unsigned short f2bf(float f) {
  uint32_t u = __builtin_bit_cast(uint32_t, f);
  u += 0x7fffu + ((u >> 16) & 1u);   // round-to-nearest-even
  return (unsigned short)(u >> 16);
}

__device__ inline u16x8 cvt8(const float* __restrict__ src) {
  float4 f0 = *(const float4*)src;
  float4 f1 = *(const float4*)(src + 4);
  u16x8 v;
  v[0] = f2bf(f0.x); v[1] = f2bf(f0.y); v[2] = f2bf(f0.z); v[3] = f2bf(f0.w);
  v[4] = f2bf(f1.x); v[5] = f2bf(f1.y); v[6] = f2bf(f1.z); v[7] = f2bf(f1.w);
  return v;
}

__device__ inline float sigmoid_f(float x) {
  float e = __builtin_amdgcn_exp2f(-1.4426950408889634f * x);
  return __builtin_amdgcn_rcpf(1.0f + e);
}
__device__ inline float tanh_f(float x) {
  float e = __builtin_amdgcn_exp2f(2.8853900817779268f * x);  // e^(2x)
  return 1.0f - 2.0f * __builtin_amdgcn_rcpf(1.0f + e);
}

// XH[b][k] = bf16( k<1024 ? x[b][k] : h_prev[b][k-1024] )
__global__ void pack_xh(const float* __restrict__ x, const float* __restrict__ hp,
                        unsigned short* __restrict__ xh) {
  const int64_t nch = (int64_t)BATCH * KDIM / 8;
  for (int64_t c = (int64_t)blockIdx.x * blockDim.x + threadIdx.x; c < nch;
       c += (int64_t)gridDim.x * blockDim.x) {
    const int b = (int)(c >> 8);          // 256 8-elem chunks per row
    const int k = ((int)c & 255) * 8;
    const float* src = (k < 1024) ? (x + (int64_t)b * 1024 + k)
                                  : (hp + (int64_t)b * 1024 + (k - 1024));
    *(u16x8*)(xh + c * 8) = cvt8(src);
  }
}

// Wp[n'][k], n' = 4*h+g: k<1024 -> Wx[g][h][k], else Rh[g][h][k-1024]
__global__ void pack_w(const float* __restrict__ Wx, const float* __restrict__ Rh,
                       unsigned short* __restrict__ wp) {
  const int64_t nch = (int64_t)NDIM * KDIM / 8;
  for (int64_t c = (int64_t)blockIdx.x * blockDim.x + threadIdx.x; c < nch;
       c += (int64_t)gridDim.x * blockDim.x) {
    const int np = (int)(c >> 8);
    const int k = ((int)c & 255) * 8;
    const int h = np >> 2, g = np & 3;
    const float* src = (k < 1024) ? (Wx + (int64_t)(g * HDIM + h) * 1024 + k)
                                  : (Rh + (int64_t)(g * HDIM + h) * 1024 + (k - 1024));
    *(u16x8*)(wp + c * 8) = cvt8(src);
  }
}

__global__ void pack_bias(const float* __restrict__ bx, const float* __restrict__ bh,
                          float* __restrict__ bias) {
  int n = blockIdx.x * blockDim.x + threadIdx.x;
  if (n < NDIM) {
    int h = n >> 2, g = n & 3;
    bias[n] = bx[g * HDIM + h] + bh[g * HDIM + h];
  }
}

// 128x128 tile GEMM (m97 structure) + XOR swizzle + fused LSTM epilogue.
__global__ __launch_bounds__(256) void lstm_gemm(
    const unsigned short* __restrict__ XH, const unsigned short* __restrict__ Wp,
    const float* __restrict__ bias, const float* __restrict__ c_prev,
    float* __restrict__ out_h, float* __restrict__ out_c) {
  // A tile [128 rows][64 bf16] at smem+0, B tile at smem+16384.
  // Epilogue reuses this space after the final barrier (wave-private regions).
  __shared__ char smem[32768];
  unsigned short* Alds = (unsigned short*)smem;
  unsigned short* Blds = (unsigned short*)(smem + 16384);

  const int tid  = threadIdx.x;
  const int lane = tid & 63;
  const int w    = tid >> 6;
  const int wr   = w >> 1, wc = w & 1;

  // XCD-aware swizzle: xcd owns 4 tile_n columns (B-panel 2MB, L2-resident);
  // consecutive q share tile_m (A-panel L2 reuse across the 4 tile_n).
  const int bid = blockIdx.x;
  const int xcd = bid & 7;
  const int q   = bid >> 3;
  const int tn  = xcd * 4 + (q & 3);
  const int tm  = q >> 2;
  const int m0  = tm * 128;
  const int n0  = tn * 128;

  // Staging: thread loads row r = s*32 + tid/8; LDS dest chunk (tid&7) must hold
  // global chunk (tid&7) ^ (r&7)  [r&7 == (tid>>3)&7, s-invariant] -> LDS content
  // is the XOR-swizzled layout while global_load_lds dest stays linear (rule #21).
  const int csrc = (((tid & 7) ^ ((tid >> 3) & 7)) * 16);   // byte offset in 128B slab
  const char* agp = (const char*)XH + (int64_t)(m0 + (tid >> 3)) * KDIM * 2 + csrc;
  const char* bgp = (const char*)Wp + (int64_t)(n0 + (tid >> 3)) * KDIM * 2 + csrc;
  char* aldsw = (char*)Alds + w * 1024;   // wave-uniform LDS dest base
  char* bldsw = (char*)Blds + w * 1024;

  const int la = lane & 15;
  const int kg = lane >> 4;
  const int sw = la & 7;                  // row&7 for this lane's fragment rows
  const uint32_t arow = (uint32_t)(64 * wr + la) * 128;
  const uint32_t brow = (uint32_t)(64 * wc + la) * 128;
  const uint32_t kc[2] = { (uint32_t)((kg ^ sw) << 4), (uint32_t)(((kg + 4) ^ sw) << 4) };

  f32x4 acc[4][4] = {};

  for (int kt = 0; kt < KDIM / 64; ++kt) {
#pragma unroll
    for (int s = 0; s < 4; ++s)
      __builtin_amdgcn_global_load_lds((const AS1 void*)(agp + (int64_t)s * 131072 + kt * 128),
                                       (AS3 void*)(aldsw + s * 4096), 16, 0, 0);
#pragma unroll
    for (int s = 0; s < 4; ++s)
      __builtin_amdgcn_global_load_lds((const AS1 void*)(bgp + (int64_t)s * 131072 + kt * 128),
                                       (AS3 void*)(bldsw + s * 4096), 16, 0, 0);
    __syncthreads();
#pragma unroll
    for (int kh = 0; kh < 2; ++kh) {
      bf16x8 af[4], bfr[4];
#pragma unroll
      for (int mi = 0; mi < 4; ++mi)
        af[mi] = *(const bf16x8*)((const char*)Alds + arow + mi * 2048 + kc[kh]);
#pragma unroll
      for (int ni = 0; ni < 4; ++ni)
        bfr[ni] = *(const bf16x8*)((const char*)Blds + brow + ni * 2048 + kc[kh]);
#pragma unroll
      for (int mi = 0; mi < 4; ++mi)
#pragma unroll
        for (int ni = 0; ni < 4; ++ni)
          acc[mi][ni] = __builtin_amdgcn_mfma_f32_16x16x32_bf16(af[mi], bfr[ni], acc[mi][ni], 0, 0, 0);
    }
    __syncthreads();
  }

  // ---- fused epilogue (reuses staging LDS; wave-private, no barrier needed) ----
  // wave owns rows [m0+64wr, +64), cols n' [n0+64wc, +64) -> h in [hbase, hbase+16)
  const int hbase = (n0 + 64 * wc) >> 2;
  const float4 bias4 = *(const float4*)(bias + n0 + 64 * wc + 4 * la);
  float* ew = (float*)smem + w * 1088;    // 16 rows x 68 floats per wave (17408B total)

#pragma unroll
  for (int mi = 0; mi < 4; ++mi) {
    // stash 16x64 fp32 fragment block
#pragma unroll
    for (int ni = 0; ni < 4; ++ni)
#pragma unroll
      for (int r = 0; r < 4; ++r)
        ew[(4 * kg + r) * 68 + ni * 16 + la] = acc[mi][ni][r];
#pragma unroll
    for (int p = 0; p < 4; ++p) {
      const int row = p * 4 + kg;
      float4 g4 = *(const float4*)(ew + row * 68 + 4 * la);   // z,i,f,o for one (b,h)
      const int b  = m0 + 64 * wr + mi * 16 + row;
      const int hg = hbase + la;
      const uint32_t oidx = (uint32_t)b * HDIM + (uint32_t)hg;
      const float cp = c_prev[oidx];
      const float zg = tanh_f(g4.x + bias4.x);
      const float ig = sigmoid_f(g4.y + bias4.y);
      const float fg = sigmoid_f(g4.z + bias4.z);
      const float og = sigmoid_f(g4.w + bias4.w);
      const float cn = fg * cp + ig * zg;
      out_h[oidx] = og * tanh_f(cn);
      out_c[oidx] = cn;
    }
  }
}

extern "C" void kernel_launch(void* const* d_in, const int* in_sizes, int n_in,
                              void* d_out, int out_size, void* d_ws, size_t ws_size,
                              hipStream_t stream) {
  const float* x  = (const float*)d_in[0];
  const float* hp = (const float*)d_in[1];
  const float* cp = (const float*)d_in[2];
  const float* Wx = (const float*)d_in[3];
  const float* bx = (const float*)d_in[4];
  const float* Rh = (const float*)d_in[5];
  const float* bh = (const float*)d_in[6];

  unsigned short* XH = (unsigned short*)d_ws;                 // 64 MB
  unsigned short* Wp = XH + (size_t)BATCH * KDIM;             // 16 MB
  float* bias = (float*)(Wp + (size_t)NDIM * KDIM);           // 16 KB
  float* out_h = (float*)d_out;
  float* out_c = out_h + (size_t)BATCH * HDIM;

  pack_xh<<<2048, 256, 0, stream>>>(x, hp, XH);
  pack_w<<<1024, 256, 0, stream>>>(Wx, Rh, Wp);
  pack_bias<<<16, 256, 0, stream>>>(bx, bh, bias);
  lstm_gemm<<<4096, 256, 0, stream>>>(XH, Wp, bias, cp, out_h, out_c);
}

// Round 3
// 314.758 us; speedup vs baseline: 1.4151x; 1.1241x over previous
//
#include <hip/hip_runtime.h>
#include <hip/hip_bf16.h>
#include <stdint.h>

// LSTM block: pre = [x|h_prev] @ [Wx|Rh]^T + bias; gates z,i,f,o; c = f*c_prev + i*z; h = o*tanh(c)
// GEMM M=16384 N=4096(n'=4h+g) K=2048 bf16 MFMA, fused epilogue.
// R3: 256x256 8-phase schedule (T2 swizzle + T3/T4 counted vmcnt + T5 setprio).

typedef __attribute__((ext_vector_type(8))) short bf16x8;
typedef __attribute__((ext_vector_type(4))) float f32x4;
typedef __attribute__((ext_vector_type(8))) unsigned short u16x8;

#define AS1 __attribute__((address_space(1)))
#define AS3 __attribute__((address_space(3)))

constexpr int BATCH = 16384;
constexpr int HDIM  = 1024;
constexpr int KDIM  = 2048;
constexpr int NDIM  = 4096;

__device__ inline unsigned short f2bf(float f) {
  uint32_t u = __builtin_bit_cast(uint32_t, f);
  u += 0x7fffu + ((u >> 16) & 1u);
  return (unsigned short)(u >> 16);
}
__device__ inline u16x8 cvt8(const float* __restrict__ src) {
  float4 f0 = *(const float4*)src;
  float4 f1 = *(const float4*)(src + 4);
  u16x8 v;
  v[0] = f2bf(f0.x); v[1] = f2bf(f0.y); v[2] = f2bf(f0.z); v[3] = f2bf(f0.w);
  v[4] = f2bf(f1.x); v[5] = f2bf(f1.y); v[6] = f2bf(f1.z); v[7] = f2bf(f1.w);
  return v;
}
__device__ inline float sigmoid_f(float x) {
  float e = __builtin_amdgcn_exp2f(-1.4426950408889634f * x);
  return __builtin_amdgcn_rcpf(1.0f + e);
}
__device__ inline float tanh_f(float x) {
  float e = __builtin_amdgcn_exp2f(2.8853900817779268f * x);
  return 1.0f - 2.0f * __builtin_amdgcn_rcpf(1.0f + e);
}

__global__ void pack_xh(const float* __restrict__ x, const float* __restrict__ hp,
                        unsigned short* __restrict__ xh) {
  const int64_t nch = (int64_t)BATCH * KDIM / 8;
  for (int64_t c = (int64_t)blockIdx.x * blockDim.x + threadIdx.x; c < nch;
       c += (int64_t)gridDim.x * blockDim.x) {
    const int b = (int)(c >> 8);
    const int k = ((int)c & 255) * 8;
    const float* src = (k < 1024) ? (x + (int64_t)b * 1024 + k)
                                  : (hp + (int64_t)b * 1024 + (k - 1024));
    *(u16x8*)(xh + c * 8) = cvt8(src);
  }
}
__global__ void pack_w(const float* __restrict__ Wx, const float* __restrict__ Rh,
                       unsigned short* __restrict__ wp) {
  const int64_t nch = (int64_t)NDIM * KDIM / 8;
  for (int64_t c = (int64_t)blockIdx.x * blockDim.x + threadIdx.x; c < nch;
       c += (int64_t)gridDim.x * blockDim.x) {
    const int np = (int)(c >> 8);
    const int k = ((int)c & 255) * 8;
    const int h = np >> 2, g = np & 3;
    const float* src = (k < 1024) ? (Wx + (int64_t)(g * HDIM + h) * 1024 + k)
                                  : (Rh + (int64_t)(g * HDIM + h) * 1024 + (k - 1024));
    *(u16x8*)(wp + c * 8) = cvt8(src);
  }
}
__global__ void pack_bias(const float* __restrict__ bx, const float* __restrict__ bh,
                          float* __restrict__ bias) {
  int n = blockIdx.x * blockDim.x + threadIdx.x;
  if (n < NDIM) {
    int h = n >> 2, g = n & 3;
    bias[n] = bx[g * HDIM + h] + bh[g * HDIM + h];
  }
}

template <int OFF>
__device__ __forceinline__ bf16x8 dsb128(uint32_t a) {
  bf16x8 r;
  asm volatile("ds_read_b128 %0, %1 offset:%2" : "=v"(r) : "v"(a), "i"(OFF) : "memory");
  return r;
}

#define BARR   asm volatile("s_barrier" ::: "memory")
#define LGKM0  asm volatile("s_waitcnt lgkmcnt(0)" ::: "memory")
#define VM6    asm volatile("s_waitcnt vmcnt(6)" ::: "memory")
#define VM0    asm volatile("s_waitcnt vmcnt(0)" ::: "memory")
#define SCHED0 __builtin_amdgcn_sched_barrier(0)

// LDS map (bytes): A[buf][kh] 16KB halves at buf*32768+kh*16384 (A base 0, B base 65536).
// Half layout: [256 rows][4 chunks of 16B], chunk swizzle c' = c ^ ((row>>1)&3).
#define READ_A(BUF, KH, MH) { constexpr int _o = (BUF)*32768 + (KH)*16384 + (MH)*4096; \
  fa[0] = dsb128<_o>(av); fa[1] = dsb128<_o+1024>(av);                                  \
  fa[2] = dsb128<_o+2048>(av); fa[3] = dsb128<_o+3072>(av); }
#define READ_B(BUF, KH) { constexpr int _o = (BUF)*32768 + (KH)*16384; \
  fb[0] = dsb128<_o>(bv); fb[1] = dsb128<_o+1024>(bv);                  \
  fb[2] = dsb128<_o+2048>(bv); fb[3] = dsb128<_o+3072>(bv); }

#define MFMA16(MB) { \
  __builtin_amdgcn_s_setprio(1); \
  _Pragma("unroll") for (int j = 0; j < 4; ++j) \
  _Pragma("unroll") for (int ni = 0; ni < 4; ++ni) \
    acc[(MB)*4 + j][ni] = __builtin_amdgcn_mfma_f32_16x16x32_bf16(fa[j], fb[ni], acc[(MB)*4 + j][ni], 0, 0, 0); \
  __builtin_amdgcn_s_setprio(0); }

#define STAGE(SRC, DOFF) { \
  __builtin_amdgcn_global_load_lds((const AS1 void*)(SRC), (AS3 void*)(dstL + (DOFF)), 16, 0, 0); \
  __builtin_amdgcn_global_load_lds((const AS1 void*)((SRC) + 524288), (AS3 void*)(dstL + (DOFF) + 8192), 16, 0, 0); }

__global__ __launch_bounds__(512, 2) void lstm_gemm(
    const unsigned short* __restrict__ XH, const unsigned short* __restrict__ Wp,
    const float* __restrict__ bias, const float* __restrict__ c_prev,
    float* __restrict__ out_h, float* __restrict__ out_c) {
  __shared__ __align__(1024) char smem_[131072];

  const int tid  = threadIdx.x;
  const int l    = tid & 63;
  const int w    = tid >> 6;          // 8 waves: 2M x 4N
  const int wr   = w >> 2, wc = w & 3;
  const int la   = l & 15;
  const int kg   = l >> 4;

  // XCD swizzle: xcd owns tn pair (B-panel 2 x 1MB L2-resident), tm-major within.
  const int xcd = blockIdx.x & 7;
  const int q   = blockIdx.x >> 3;          // [0,128)
  const int tn  = xcd * 2 + (q & 1);
  const int tm  = q >> 1;
  const int m0  = tm * 256;
  const int n0  = tn * 256;

  // Staging: lane l of wave w, load i: row = w*16 + (l>>2) + i*128, chunk c = l&3,
  // source k-chunk = c ^ ((row>>1)&3) = (l&3) ^ ((l>>3)&3). LDS dest linear.
  const int rbase = w * 16 + (l >> 2);
  const int ck    = (l & 3) ^ ((l >> 3) & 3);
  const char* pA = (const char*)XH + (int64_t)(m0 + rbase) * 4096 + ck * 16;
  const char* pB = (const char*)Wp + (int64_t)(n0 + rbase) * 4096 + ck * 16;
  char* dstL = smem_ + w * 1024;            // wave-uniform; HW adds lane*16

  // Fragment read addresses: row*64 + (kg ^ ((la>>1)&3))*16, row = (wr*128|wc*64) + sub + la
  const int cc = kg ^ ((la >> 1) & 3);
  const uint32_t lds0 = (uint32_t)(uintptr_t)(AS3 char*)smem_;
  const uint32_t av = lds0 + wr * 8192 + la * 64 + cc * 16;
  const uint32_t bv = lds0 + 65536 + wc * 4096 + la * 64 + cc * 16;

  f32x4 acc[8][4] = {};
  bf16x8 fa[4], fb[4];

  // Prologue: tile0 all 4 halves + tile1 {B.kh0, A.kh0, B.kh1}; wait tile0 landed.
  STAGE(pB,       65536);   // t0.B.kh0
  STAGE(pA,       0);       // t0.A.kh0
  STAGE(pB + 64,  81920);   // t0.B.kh1
  STAGE(pA + 64,  16384);   // t0.A.kh1
  STAGE(pB + 128, 98304);   // t1.B.kh0
  STAGE(pA + 128, 32768);   // t1.A.kh0
  STAGE(pB + 192, 114688);  // t1.B.kh1
  VM6; BARR;

#pragma unroll 1
  for (int it = 0; it < 16; ++it) {
    int kt2 = 2 * it + 2; if (kt2 > 31) kt2 = 31;
    int kt3 = 2 * it + 3; if (kt3 > 31) kt3 = 31;
    const char* sA1 = pA + (2 * it + 1) * 128;
    const char* sA2 = pA + kt2 * 128;
    const char* sA3 = pA + kt3 * 128;
    const char* sB2 = pB + kt2 * 128;
    const char* sB3 = pB + kt3 * 128;

    // ph0: tile t, kh0, mh0
    READ_B(0, 0) READ_A(0, 0, 0)
    STAGE(sA1 + 64, 49152);          // t+1.A.kh1 -> buf1.A.kh1 (dead since prev ph7)
    BARR; LGKM0; SCHED0; MFMA16(0) BARR;
    // ph1: tile t, kh0, mh1
    READ_A(0, 0, 1)
    STAGE(sB2, 65536);               // t+2.B.kh0 -> buf0.B.kh0 (dead after ph0)
    BARR; LGKM0; SCHED0; MFMA16(1) BARR;
    // ph2: tile t, kh1, mh0
    READ_B(0, 1) READ_A(0, 1, 0)
    STAGE(sA2, 0);                   // t+2.A.kh0 (dead after ph1)
    BARR; LGKM0; SCHED0; MFMA16(0) BARR;
    // ph3: tile t, kh1, mh1
    READ_A(0, 1, 1)
    STAGE(sB2 + 64, 81920);          // t+2.B.kh1 (dead after ph2)
    BARR; LGKM0; SCHED0; MFMA16(1) VM6; BARR;
    // ph4: tile t+1, kh0, mh0
    READ_B(1, 0) READ_A(1, 0, 0)
    STAGE(sA2 + 64, 16384);          // t+2.A.kh1 (dead after ph3)
    BARR; LGKM0; SCHED0; MFMA16(0) BARR;
    // ph5: tile t+1, kh0, mh1
    READ_A(1, 0, 1)
    STAGE(sB3, 98304);               // t+3.B.kh0 (dead after ph4)
    BARR; LGKM0; SCHED0; MFMA16(1) BARR;
    // ph6: tile t+1, kh1, mh0
    READ_B(1, 1) READ_A(1, 1, 0)
    STAGE(sA3, 32768);               // t+3.A.kh0 (dead after ph5)
    BARR; LGKM0; SCHED0; MFMA16(0) BARR;
    // ph7: tile t+1, kh1, mh1
    READ_A(1, 1, 1)
    STAGE(sB3 + 64, 114688);         // t+3.B.kh1 (dead after ph6)
    BARR; LGKM0; SCHED0; MFMA16(1) VM6; BARR;
  }

  // ---- fused LSTM epilogue (drain tail stages, then reuse LDS; wave-private) ----
  VM0;
  __syncthreads();
  float* ew = (float*)smem_ + w * 1088;     // 16 x 68 floats per wave
  const float4 bias4 = *(const float4*)(bias + n0 + wc * 64 + 4 * la);
  const int hg = ((n0 + wc * 64) >> 2) + la;

#pragma unroll
  for (int mi = 0; mi < 8; ++mi) {
#pragma unroll
    for (int ni = 0; ni < 4; ++ni)
#pragma unroll
      for (int r = 0; r < 4; ++r)
        ew[(4 * kg + r) * 68 + ni * 16 + la] = acc[mi][ni][r];
#pragma unroll
    for (int p = 0; p < 4; ++p) {
      const int row = p * 4 + kg;
      float4 g4 = *(const float4*)(ew + row * 68 + 4 * la);   // z,i,f,o for one (b,h)
      const int b = m0 + wr * 128 + mi * 16 + row;
      const uint32_t oidx = (uint32_t)b * HDIM + (uint32_t)hg;
      const float cp = c_prev[oidx];
      const float zg = tanh_f(g4.x + bias4.x);
      const float ig = sigmoid_f(g4.y + bias4.y);
      const float fg = sigmoid_f(g4.z + bias4.z);
      const float og = sigmoid_f(g4.w + bias4.w);
      const float cn = fg * cp + ig * zg;
      out_h[oidx] = og * tanh_f(cn);
      out_c[oidx] = cn;
    }
  }
}

extern "C" void kernel_launch(void* const* d_in, const int* in_sizes, int n_in,
                              void* d_out, int out_size, void* d_ws, size_t ws_size,
                              hipStream_t stream) {
  const float* x  = (const float*)d_in[0];
  const float* hp = (const float*)d_in[1];
  const float* cp = (const float*)d_in[2];
  const float* Wx = (const float*)d_in[3];
  const float* bx = (const float*)d_in[4];
  const float* Rh = (const float*)d_in[5];
  const float* bh = (const float*)d_in[6];

  unsigned short* XH = (unsigned short*)d_ws;                 // 64 MB
  unsigned short* Wp = XH + (size_t)BATCH * KDIM;             // 16 MB
  float* bias = (float*)(Wp + (size_t)NDIM * KDIM);           // 16 KB
  float* out_h = (float*)d_out;
  float* out_c = out_h + (size_t)BATCH * HDIM;

  pack_xh<<<2048, 256, 0, stream>>>(x, hp, XH);
  pack_w<<<1024, 256, 0, stream>>>(Wx, Rh, Wp);
  pack_bias<<<16, 256, 0, stream>>>(bx, bh, bias);
  lstm_gemm<<<1024, 512, 0, stream>>>(XH, Wp, bias, cp, out_h, out_c);
}

// Round 4
// 306.514 us; speedup vs baseline: 1.4531x; 1.0269x over previous
//
#include <hip/hip_runtime.h>
#include <hip/hip_bf16.h>
#include <stdint.h>

// LSTM block: pre = [x|h_prev] @ [Wx|Rh]^T + bias; gates z,i,f,o; c = f*c_prev + i*z; h = o*tanh(c)
// GEMM M=16384 N=4096(n'=4h+g) K=2048 bf16 MFMA, fused epilogue.
// R4: counted-lgkmcnt read-ahead (frag double-buffer), 1 barrier/phase, VM6 at odd-phase ends.

typedef __attribute__((ext_vector_type(8))) short bf16x8;
typedef __attribute__((ext_vector_type(4))) float f32x4;
typedef __attribute__((ext_vector_type(8))) unsigned short u16x8;

#define AS1 __attribute__((address_space(1)))
#define AS3 __attribute__((address_space(3)))

constexpr int BATCH = 16384;
constexpr int HDIM  = 1024;
constexpr int KDIM  = 2048;
constexpr int NDIM  = 4096;

__device__ inline unsigned short f2bf(float f) {
  uint32_t u = __builtin_bit_cast(uint32_t, f);
  u += 0x7fffu + ((u >> 16) & 1u);
  return (unsigned short)(u >> 16);
}
__device__ inline u16x8 cvt8(const float* __restrict__ src) {
  float4 f0 = *(const float4*)src;
  float4 f1 = *(const float4*)(src + 4);
  u16x8 v;
  v[0] = f2bf(f0.x); v[1] = f2bf(f0.y); v[2] = f2bf(f0.z); v[3] = f2bf(f0.w);
  v[4] = f2bf(f1.x); v[5] = f2bf(f1.y); v[6] = f2bf(f1.z); v[7] = f2bf(f1.w);
  return v;
}
__device__ inline float sigmoid_f(float x) {
  float e = __builtin_amdgcn_exp2f(-1.4426950408889634f * x);
  return __builtin_amdgcn_rcpf(1.0f + e);
}
__device__ inline float tanh_f(float x) {
  float e = __builtin_amdgcn_exp2f(2.8853900817779268f * x);
  return 1.0f - 2.0f * __builtin_amdgcn_rcpf(1.0f + e);
}

__global__ void pack_xh(const float* __restrict__ x, const float* __restrict__ hp,
                        unsigned short* __restrict__ xh) {
  const int64_t nch = (int64_t)BATCH * KDIM / 8;
  for (int64_t c = (int64_t)blockIdx.x * blockDim.x + threadIdx.x; c < nch;
       c += (int64_t)gridDim.x * blockDim.x) {
    const int b = (int)(c >> 8);
    const int k = ((int)c & 255) * 8;
    const float* src = (k < 1024) ? (x + (int64_t)b * 1024 + k)
                                  : (hp + (int64_t)b * 1024 + (k - 1024));
    *(u16x8*)(xh + c * 8) = cvt8(src);
  }
}
__global__ void pack_w(const float* __restrict__ Wx, const float* __restrict__ Rh,
                       unsigned short* __restrict__ wp) {
  const int64_t nch = (int64_t)NDIM * KDIM / 8;
  for (int64_t c = (int64_t)blockIdx.x * blockDim.x + threadIdx.x; c < nch;
       c += (int64_t)gridDim.x * blockDim.x) {
    const int np = (int)(c >> 8);
    const int k = ((int)c & 255) * 8;
    const int h = np >> 2, g = np & 3;
    const float* src = (k < 1024) ? (Wx + (int64_t)(g * HDIM + h) * 1024 + k)
                                  : (Rh + (int64_t)(g * HDIM + h) * 1024 + (k - 1024));
    *(u16x8*)(wp + c * 8) = cvt8(src);
  }
}
__global__ void pack_bias(const float* __restrict__ bx, const float* __restrict__ bh,
                          float* __restrict__ bias) {
  int n = blockIdx.x * blockDim.x + threadIdx.x;
  if (n < NDIM) {
    int h = n >> 2, g = n & 3;
    bias[n] = bx[g * HDIM + h] + bh[g * HDIM + h];
  }
}

template <int OFF>
__device__ __forceinline__ bf16x8 dsb128(uint32_t a) {
  bf16x8 r;
  asm volatile("ds_read_b128 %0, %1 offset:%2" : "=v"(r) : "v"(a), "i"(OFF) : "memory");
  return r;
}

#define BARR   asm volatile("s_barrier" ::: "memory")
#define LGKM4  asm volatile("s_waitcnt lgkmcnt(4)" ::: "memory")
#define LGKM8  asm volatile("s_waitcnt lgkmcnt(8)" ::: "memory")
#define VM6    asm volatile("s_waitcnt vmcnt(6)" ::: "memory")
#define VM0    asm volatile("s_waitcnt vmcnt(0)" ::: "memory")
#define SCHED0 __builtin_amdgcn_sched_barrier(0)

// LDS map (bytes): A halves 16KB at buf*32768+kh*16384 (A base 0, B base 65536).
// Half layout: [256 rows][4 chunks of 16B], chunk swizzle c' = c ^ ((row>>1)&3).
#define ISS_A(FA, BUF, KH, MH) { constexpr int _o = (BUF)*32768 + (KH)*16384 + (MH)*4096; \
  FA[0] = dsb128<_o>(av); FA[1] = dsb128<_o+1024>(av);                                     \
  FA[2] = dsb128<_o+2048>(av); FA[3] = dsb128<_o+3072>(av); }
#define ISS_B(FB, BUF, KH) { constexpr int _o = (BUF)*32768 + (KH)*16384; \
  FB[0] = dsb128<_o>(bv); FB[1] = dsb128<_o+1024>(bv);                     \
  FB[2] = dsb128<_o+2048>(bv); FB[3] = dsb128<_o+3072>(bv); }

#define MFMA16(FA, FB, MB) { \
  __builtin_amdgcn_s_setprio(1); \
  _Pragma("unroll") for (int j = 0; j < 4; ++j) \
  _Pragma("unroll") for (int ni = 0; ni < 4; ++ni) \
    acc[(MB)*4 + j][ni] = __builtin_amdgcn_mfma_f32_16x16x32_bf16(FA[j], FB[ni], acc[(MB)*4 + j][ni], 0, 0, 0); \
  __builtin_amdgcn_s_setprio(0); }

#define STAGE(SRC, DOFF) { \
  __builtin_amdgcn_global_load_lds((const AS1 void*)(SRC), (AS3 void*)(dstL + (DOFF)), 16, 0, 0); \
  __builtin_amdgcn_global_load_lds((const AS1 void*)((SRC) + 524288), (AS3 void*)(dstL + (DOFF) + 8192), 16, 0, 0); }

__global__ __launch_bounds__(512, 2) void lstm_gemm(
    const unsigned short* __restrict__ XH, const unsigned short* __restrict__ Wp,
    const float* __restrict__ bias, const float* __restrict__ c_prev,
    float* __restrict__ out_h, float* __restrict__ out_c) {
  __shared__ __align__(1024) char smem_[131072];

  const int tid  = threadIdx.x;
  const int l    = tid & 63;
  const int w    = tid >> 6;          // 8 waves: 2M x 4N
  const int wr   = w >> 2, wc = w & 3;
  const int la   = l & 15;
  const int kg   = l >> 4;

  // XCD swizzle: xcd owns tn pair (B-panel 2 x 1MB L2-resident), tm-major within.
  const int xcd = blockIdx.x & 7;
  const int q   = blockIdx.x >> 3;
  const int tn  = xcd * 2 + (q & 1);
  const int tm  = q >> 1;
  const int m0  = tm * 256;
  const int n0  = tn * 256;

  // Staging: lane l of wave w, load i: row = w*16 + (l>>2) + i*128, chunk c = l&3,
  // source k-chunk = c ^ ((row>>1)&3) = (l&3) ^ ((l>>3)&3). LDS dest linear.
  const int rbase = w * 16 + (l >> 2);
  const int ck    = (l & 3) ^ ((l >> 3) & 3);
  const char* pA = (const char*)XH + (int64_t)(m0 + rbase) * 4096 + ck * 16;
  const char* pB = (const char*)Wp + (int64_t)(n0 + rbase) * 4096 + ck * 16;
  char* dstL = smem_ + w * 1024;

  // Fragment read addresses: row*64 + (kg ^ ((la>>1)&3))*16
  const int cc = kg ^ ((la >> 1) & 3);
  const uint32_t lds0 = (uint32_t)(uintptr_t)(AS3 char*)smem_;
  const uint32_t av = lds0 + wr * 8192 + la * 64 + cc * 16;
  const uint32_t bv = lds0 + 65536 + wc * 4096 + la * 64 + cc * 16;

  f32x4 acc[8][4] = {};
  bf16x8 fa0[4], fa1[4], fb0[4], fb1[4];

  // Prologue: stage t0 (4 halves) + t1 {B.kh0, A.kh0, B.kh1}; gate t0; issue ph0 reads.
  STAGE(pB,       65536);   // t0.B.kh0
  STAGE(pA,       0);       // t0.A.kh0
  STAGE(pB + 64,  81920);   // t0.B.kh1
  STAGE(pA + 64,  16384);   // t0.A.kh1
  STAGE(pB + 128, 98304);   // t1.B.kh0
  STAGE(pA + 128, 32768);   // t1.A.kh0
  STAGE(pB + 192, 114688);  // t1.B.kh1
  VM6; BARR;
  ISS_B(fb0, 0, 0) ISS_A(fa0, 0, 0, 0)

#pragma unroll 1
  for (int it = 0; it < 16; ++it) {
    int kt2 = 2 * it + 2; if (kt2 > 31) kt2 = 31;
    int kt3 = 2 * it + 3; if (kt3 > 31) kt3 = 31;
    const char* sA1 = pA + (2 * it + 1) * 128;
    const char* sA2 = pA + kt2 * 128;
    const char* sA3 = pA + kt3 * 128;
    const char* sB2 = pB + kt2 * 128;
    const char* sB3 = pB + kt3 * 128;

    // ph0: consume (fa0,fb0)=t.kh0.mh0; issue fa1 <- t.kh0.mh1
    BARR;
    STAGE(sA1 + 64, 49152);          // t+1.A.kh1 (dead since prev ph7 consume)
    ISS_A(fa1, 0, 0, 1)
    LGKM4; SCHED0; MFMA16(fa0, fb0, 0)
    // ph1: consume (fa1,fb0); issue (fb1,fa0) <- t.kh1
    BARR;
    STAGE(sB2, 65536);               // t+2.B.kh0
    ISS_B(fb1, 0, 1) ISS_A(fa0, 0, 1, 0)
    LGKM8; SCHED0; MFMA16(fa1, fb0, 1)
    VM6;
    // ph2: consume (fa0,fb1); issue fa1 <- t.kh1.mh1
    BARR;
    STAGE(sA2, 0);                   // t+2.A.kh0
    ISS_A(fa1, 0, 1, 1)
    LGKM4; SCHED0; MFMA16(fa0, fb1, 0)
    // ph3: consume (fa1,fb1); issue (fb0,fa0) <- t+1.kh0
    BARR;
    STAGE(sB2 + 64, 81920);          // t+2.B.kh1
    ISS_B(fb0, 1, 0) ISS_A(fa0, 1, 0, 0)
    LGKM8; SCHED0; MFMA16(fa1, fb1, 1)
    VM6;
    // ph4: consume (fa0,fb0); issue fa1 <- t+1.kh0.mh1
    BARR;
    STAGE(sA2 + 64, 16384);          // t+2.A.kh1
    ISS_A(fa1, 1, 0, 1)
    LGKM4; SCHED0; MFMA16(fa0, fb0, 0)
    // ph5: consume (fa1,fb0); issue (fb1,fa0) <- t+1.kh1
    BARR;
    STAGE(sB3, 98304);               // t+3.B.kh0
    ISS_B(fb1, 1, 1) ISS_A(fa0, 1, 1, 0)
    LGKM8; SCHED0; MFMA16(fa1, fb0, 1)
    VM6;
    // ph6: consume (fa0,fb1); issue fa1 <- t+1.kh1.mh1
    BARR;
    STAGE(sA3, 32768);               // t+3.A.kh0
    ISS_A(fa1, 1, 1, 1)
    LGKM4; SCHED0; MFMA16(fa0, fb1, 0)
    // ph7: consume (fa1,fb1); issue (fb0,fa0) <- next-iter t.kh0
    BARR;
    STAGE(sB3 + 64, 114688);         // t+3.B.kh1
    ISS_B(fb0, 0, 0) ISS_A(fa0, 0, 0, 0)
    LGKM8; SCHED0; MFMA16(fa1, fb1, 1)
    VM6;
  }

  // ---- fused LSTM epilogue (drain, then reuse LDS; wave-private) ----
  VM0;
  __syncthreads();
  float* ew = (float*)smem_ + w * 1088;     // 16 x 68 floats per wave
  const float4 bias4 = *(const float4*)(bias + n0 + wc * 64 + 4 * la);
  const int hg = ((n0 + wc * 64) >> 2) + la;

#pragma unroll
  for (int mi = 0; mi < 8; ++mi) {
#pragma unroll
    for (int ni = 0; ni < 4; ++ni)
#pragma unroll
      for (int r = 0; r < 4; ++r)
        ew[(4 * kg + r) * 68 + ni * 16 + la] = acc[mi][ni][r];
#pragma unroll
    for (int p = 0; p < 4; ++p) {
      const int row = p * 4 + kg;
      float4 g4 = *(const float4*)(ew + row * 68 + 4 * la);   // z,i,f,o for one (b,h)
      const int b = m0 + wr * 128 + mi * 16 + row;
      const uint32_t oidx = (uint32_t)b * HDIM + (uint32_t)hg;
      const float cp = c_prev[oidx];
      const float zg = tanh_f(g4.x + bias4.x);
      const float ig = sigmoid_f(g4.y + bias4.y);
      const float fg = sigmoid_f(g4.z + bias4.z);
      const float og = sigmoid_f(g4.w + bias4.w);
      const float cn = fg * cp + ig * zg;
      out_h[oidx] = og * tanh_f(cn);
      out_c[oidx] = cn;
    }
  }
}

extern "C" void kernel_launch(void* const* d_in, const int* in_sizes, int n_in,
                              void* d_out, int out_size, void* d_ws, size_t ws_size,
                              hipStream_t stream) {
  const float* x  = (const float*)d_in[0];
  const float* hp = (const float*)d_in[1];
  const float* cp = (const float*)d_in[2];
  const float* Wx = (const float*)d_in[3];
  const float* bx = (const float*)d_in[4];
  const float* Rh = (const float*)d_in[5];
  const float* bh = (const float*)d_in[6];

  unsigned short* XH = (unsigned short*)d_ws;                 // 64 MB
  unsigned short* Wp = XH + (size_t)BATCH * KDIM;             // 16 MB
  float* bias = (float*)(Wp + (size_t)NDIM * KDIM);           // 16 KB
  float* out_h = (float*)d_out;
  float* out_c = out_h + (size_t)BATCH * HDIM;

  pack_xh<<<2048, 256, 0, stream>>>(x, hp, XH);
  pack_w<<<1024, 256, 0, stream>>>(Wx, Rh, Wp);
  pack_bias<<<16, 256, 0, stream>>>(bx, bh, bias);
  lstm_gemm<<<1024, 512, 0, stream>>>(XH, Wp, bias, cp, out_h, out_c);
}